// Round 4
// baseline (510.700 us; speedup 1.0000x reference)
//
#include <hip/hip_runtime.h>
#include <hip/hip_fp16.h>

// Softmax attention (mask is a no-op). B=4, S=4096, D=256, fp32 in/out.
// Round 4: fix round-3's P-write typo (chunk-1 key byte offset was
// (32+lrow)*2, overflowing the 64-B P row; must be (16+lrow)*2).
// Also: V LDS chunk swizzle c4 ^ ((d>>1)&3) on BOTH stage-source and read
// (the "linear" V layout was 8-way bank-conflicted: d-stride 64B).
//  - 256-thr blocks (4 waves x 32q = 128 q rows), KV tile = 32 keys
//  - LDS 72KB -> 2 blocks/CU; split-K=4 (fallback 2) + combine kernel
//  - tile-wide rescale decision (round-3 fix, kept)

typedef _Float16 f16x8 __attribute__((ext_vector_type(8)));
typedef _Float16 f16x4 __attribute__((ext_vector_type(4)));
typedef float    f32x4 __attribute__((ext_vector_type(4)));

#define MFMA16(A, B, C) __builtin_amdgcn_mfma_f32_16x16x32_f16((A), (B), (C), 0, 0, 0)

static __device__ __forceinline__ void gload16(const _Float16* g, _Float16* l) {
    __builtin_amdgcn_global_load_lds(
        (unsigned int __attribute__((address_space(1)))*)g,
        (unsigned int __attribute__((address_space(3)))*)l, 16, 0, 0);
}

// ---------------- kernel 0: convert x to fp16 hi/lo ----------------
__global__ __launch_bounds__(256) void convert_x_kernel(
    const float* __restrict__ x, _Float16* __restrict__ xh, _Float16* __restrict__ xl)
{
    int i = blockIdx.x * 256 + threadIdx.x;
    float4 v = ((const float4*)x)[i];
    float vv0 = v.x, vv1 = v.y, vv2 = v.z, vv3 = v.w;
    f16x4 h, l;
    _Float16 h0 = (_Float16)vv0; h[0] = h0; l[0] = (_Float16)(vv0 - (float)h0);
    _Float16 h1 = (_Float16)vv1; h[1] = h1; l[1] = (_Float16)(vv1 - (float)h1);
    _Float16 h2 = (_Float16)vv2; h[2] = h2; l[2] = (_Float16)(vv2 - (float)h2);
    _Float16 h3 = (_Float16)vv3; h[3] = h3; l[3] = (_Float16)(vv3 - (float)h3);
    ((f16x4*)xh)[i] = h;
    ((f16x4*)xl)[i] = l;
}

// ---------------- kernel 1: W -> W^T hi/lo fp16 ----------------
__global__ __launch_bounds__(256) void convert_w_kernel(
    const float* __restrict__ Wq, const float* __restrict__ Wk, const float* __restrict__ Wv,
    _Float16* __restrict__ Wth, _Float16* __restrict__ Wtl)
{
    int idx = blockIdx.x * 256 + threadIdx.x;
    int mat = idx >> 16, e = idx & 65535;
    int k = e >> 8, n = e & 255;
    const float* W = (mat == 0) ? Wq : (mat == 1) ? Wk : Wv;
    float v = W[e];
    _Float16 h = (_Float16)v;
    _Float16 lo = (_Float16)(v - (float)h);
    Wth[mat * 65536 + n * 256 + k] = h;
    Wtl[mat * 65536 + n * 256 + k] = lo;
}

// ---------------- kernel 2: projections (validated round 1) ----------------
__global__ __launch_bounds__(256) void proj_kernel(
    const _Float16* __restrict__ xh, const _Float16* __restrict__ xl,
    const _Float16* __restrict__ Wth, const _Float16* __restrict__ Wtl,
    const float* __restrict__ bq, const float* __restrict__ bk, const float* __restrict__ bv,
    _Float16* __restrict__ Qf, _Float16* __restrict__ Kf, _Float16* __restrict__ Vt)
{
    const int mat = blockIdx.y;
    const int tid = threadIdx.x, wid = tid >> 6, lane = tid & 63;
    const int lrow = lane & 15, lgrp = lane >> 4;
    const int row0 = blockIdx.x * 64 + wid * 16;
    const _Float16* Wh = Wth + mat * 65536;
    const _Float16* Wl = Wtl + mat * 65536;
    const float* bias = (mat == 0) ? bq : (mat == 1) ? bk : bv;

    f32x4 acc[16];
#pragma unroll
    for (int i = 0; i < 16; ++i) acc[i] = f32x4{0.f, 0.f, 0.f, 0.f};

#pragma unroll
    for (int ks = 0; ks < 8; ++ks) {
        const int k0 = ks * 32 + lgrp * 8;
        f16x8 Ah = *(const f16x8*)(xh + (size_t)(row0 + lrow) * 256 + k0);
        f16x8 Al = *(const f16x8*)(xl + (size_t)(row0 + lrow) * 256 + k0);
#pragma unroll
        for (int nt = 0; nt < 16; ++nt) {
            const int n = nt * 16 + lrow;
            f16x8 Bh = *(const f16x8*)(Wh + n * 256 + k0);
            f16x8 Bl = *(const f16x8*)(Wl + n * 256 + k0);
            acc[nt] = MFMA16(Ah, Bh, acc[nt]);
            acc[nt] = MFMA16(Al, Bh, acc[nt]);
            acc[nt] = MFMA16(Ah, Bl, acc[nt]);
        }
    }

    const float LOG2E = 1.4426950408889634f;
#pragma unroll
    for (int nt = 0; nt < 16; ++nt) {
        const int n = nt * 16 + lrow;
        const float bb = bias[n];
        if (mat == 2) {
            const int m0 = row0 + lgrp * 4;
            f16x4 vv;
#pragma unroll
            for (int r = 0; r < 4; ++r) vv[r] = (_Float16)(acc[nt][r] + bb);
            *(f16x4*)(Vt + (size_t)n * 16384 + m0) = vv;
        } else {
            _Float16* dst = (mat == 0) ? Qf : Kf;
            const float s = (mat == 0) ? LOG2E : 1.0f;
#pragma unroll
            for (int r = 0; r < 4; ++r) {
                const int grow = row0 + lgrp * 4 + r;
                dst[(size_t)grow * 256 + n] = (_Float16)((acc[nt][r] + bb) * s);
            }
        }
    }
}

// ---------------- kernel 3: flash attention, q=32/wave, split-K ----------------
template <int NS>
__global__ __launch_bounds__(256, 2) void attn2_kernel(
    const _Float16* __restrict__ Qf, const _Float16* __restrict__ Kf,
    const _Float16* __restrict__ Vt, _Float16* __restrict__ Op01,
    _Float16* __restrict__ Op23, float* __restrict__ ml)
{
    __shared__ _Float16 Kb[2][32 * 256];   // [key][d], swizzled 16B slots
    __shared__ _Float16 Vb[2][256 * 32];   // [d][key], chunk-swizzled
    __shared__ _Float16 Pb[4][32 * 32];    // per-wave P [q][key], bit-swizzled

    const int tid = threadIdx.x, wid = tid >> 6, lane = tid & 63;
    const int lrow = lane & 15, lgrp = lane >> 4;

    // XCD-grouped decode: same (b,split) group stays on one XCD
    const int hw = blockIdx.x;
    const int xcd = hw & 7, ii = hw >> 3;
    const int gpx = NS / 2;
    const int group = xcd * gpx + (ii >> 5);
    const int qi = ii & 31;
    const int b = group / NS, split = group % NS;
    const int KS = 4096 / NS;
    const size_t bS = (size_t)b * 4096;
    const size_t qrow = bS + qi * 128 + wid * 32;
    const size_t k0g = bS + (size_t)split * KS;

    // Q resident in registers: 32 q x 256 d
    f16x8 Aq[2][8];
#pragma unroll
    for (int m = 0; m < 2; ++m)
#pragma unroll
        for (int ks = 0; ks < 8; ++ks)
            Aq[m][ks] = *(const f16x8*)(Qf + (qrow + m * 16 + lrow) * 256 + ks * 32 + lgrp * 8);

    f32x4 Oacc[2][16];
#pragma unroll
    for (int m = 0; m < 2; ++m)
#pragma unroll
        for (int i = 0; i < 16; ++i) Oacc[m][i] = f32x4{0.f, 0.f, 0.f, 0.f};
    float m_r[2][4], l_r[2][4];
#pragma unroll
    for (int m = 0; m < 2; ++m)
#pragma unroll
        for (int r = 0; r < 4; ++r) { m_r[m][r] = -1e30f; l_r[m][r] = 0.f; }

    _Float16* Pw = Pb[wid];

    auto stage = [&](int buf, int t) {
        const size_t krow = k0g + (size_t)t * 32;
#pragma unroll
        for (int it = 0; it < 4; ++it) {     // K: 1024 slots of 16B, swizzled
            const int s = it * 256 + tid;
            const int row = s >> 5, c16 = s & 31;
            gload16(Kf + (krow + row) * 256 + ((c16 ^ (row & 7)) * 8), &Kb[buf][s * 8]);
        }
#pragma unroll
        for (int it = 0; it < 4; ++it) {     // V^T: 1024 slots, chunk-swizzled
            const int s = it * 256 + tid;
            const int d = s >> 2, c4 = s & 3;
            gload16(Vt + (size_t)d * 16384 + krow + ((c4 ^ ((d >> 1) & 3)) * 8), &Vb[buf][s * 8]);
        }
    };

    stage(0, 0);
    asm volatile("s_waitcnt vmcnt(0)" ::: "memory");
    __builtin_amdgcn_s_barrier();

    const int NT = KS / 32;
    const float THR = 10.0f;   // defer-max threshold (log2 domain)
    for (int t = 0; t < NT; ++t) {
        const int cur = t & 1;
        if (t + 1 < NT) stage(cur ^ 1, t + 1);
        const _Float16* K_ = Kb[cur];
        const _Float16* V_ = Vb[cur];

        // ---- QK: full 32-key tile scored before any softmax decision ----
        f32x4 sc[2][2];  // [nt chunk][m]
#pragma unroll
        for (int nt = 0; nt < 2; ++nt) {
            sc[nt][0] = f32x4{0.f, 0.f, 0.f, 0.f};
            sc[nt][1] = f32x4{0.f, 0.f, 0.f, 0.f};
            const int key = nt * 16 + lrow;
#pragma unroll
            for (int ks = 0; ks < 8; ++ks) {
                f16x8 Bk = *(const f16x8*)(K_ + key * 256 + (((ks * 4 + lgrp) ^ (key & 7)) * 8));
                sc[nt][0] = MFMA16(Aq[0][ks], Bk, sc[nt][0]);
                sc[nt][1] = MFMA16(Aq[1][ks], Bk, sc[nt][1]);
            }
        }

        // ---- ONE tile-wide rescale decision ----
        bool ok = true;
        float mxt[2][4];
#pragma unroll
        for (int m = 0; m < 2; ++m)
#pragma unroll
            for (int r = 0; r < 4; ++r) {
                float v = fmaxf(sc[0][m][r], sc[1][m][r]);
#pragma unroll
                for (int off = 8; off > 0; off >>= 1) v = fmaxf(v, __shfl_xor(v, off));
                mxt[m][r] = v;
                ok = ok && (v <= m_r[m][r] + THR);
            }
        if (!__all(ok)) {
#pragma unroll
            for (int m = 0; m < 2; ++m)
#pragma unroll
                for (int r = 0; r < 4; ++r) {
                    const float mn = fmaxf(m_r[m][r], mxt[m][r]);
                    const float scl = exp2f(m_r[m][r] - mn);
                    m_r[m][r] = mn;
                    l_r[m][r] *= scl;
#pragma unroll
                    for (int nt2 = 0; nt2 < 16; ++nt2) Oacc[m][nt2][r] *= scl;
                }
        }
        // ---- P = exp2(sc - m_r), all written with the FINAL m_r ----
        // key byte offsets: chunk0 key=lrow -> lrow*2; chunk1 key=16+lrow
        // -> (16+lrow)*2 = 32+2*lrow  (round-3 typo had (32+lrow)*2 = row overflow)
#pragma unroll
        for (int m = 0; m < 2; ++m)
#pragma unroll
            for (int r = 0; r < 4; ++r) {
                const int row = m * 16 + lgrp * 4 + r;
                const int rb = (lgrp & 1) << 4;
                const float p0 = exp2f(sc[0][m][r] - m_r[m][r]);
                const float p1 = exp2f(sc[1][m][r] - m_r[m][r]);
                *(_Float16*)((char*)Pw + row * 64 + ((lrow * 2) ^ rb)) = (_Float16)p0;
                *(_Float16*)((char*)Pw + row * 64 + (((16 + lrow) * 2) ^ rb)) = (_Float16)p1;
                float rs = p0 + p1;
#pragma unroll
                for (int off = 8; off > 0; off >>= 1) rs += __shfl_xor(rs, off);
                l_r[m][r] += rs;
            }

        // ---- PV ----
        asm volatile("s_waitcnt lgkmcnt(0)" ::: "memory");
        __builtin_amdgcn_sched_barrier(0);
        f16x8 Ap[2];
#pragma unroll
        for (int m = 0; m < 2; ++m)
            Ap[m] = *(const f16x8*)((const char*)Pw + (m * 16 + lrow) * 64 +
                                    ((lgrp ^ ((lrow >> 2) & 1)) << 4));
#pragma unroll
        for (int nt = 0; nt < 16; ++nt) {
            const int d = nt * 16 + lrow;
            f16x8 Bv = *(const f16x8*)(V_ + d * 32 + ((lgrp ^ ((d >> 1) & 3)) * 8));
            Oacc[0][nt] = MFMA16(Ap[0], Bv, Oacc[0][nt]);
            Oacc[1][nt] = MFMA16(Ap[1], Bv, Oacc[1][nt]);
        }

        asm volatile("s_waitcnt vmcnt(0)" ::: "memory");
        __builtin_amdgcn_s_barrier();
    }

    // ---- epilogue: normalized fp16 partial + (m, l) ----
    _Float16* Op = (split < 2) ? (Op01 + (size_t)split * 4194304)
                               : (Op23 + (size_t)(split - 2) * 4194304);
#pragma unroll
    for (int m = 0; m < 2; ++m)
#pragma unroll
        for (int r = 0; r < 4; ++r) {
            const float inv = 1.0f / l_r[m][r];
            const size_t grow = qrow + m * 16 + lgrp * 4 + r;
#pragma unroll
            for (int nt = 0; nt < 16; ++nt) {
                const int d = nt * 16 + lrow;
                Op[grow * 256 + d] = (_Float16)(Oacc[m][nt][r] * inv);
            }
            if (lrow == 0) {
                ml[((size_t)split * 16384 + grow) * 2]     = m_r[m][r];
                ml[((size_t)split * 16384 + grow) * 2 + 1] = l_r[m][r];
            }
        }
}

// ---------------- kernel 4: combine split-K partials ----------------
template <int NS>
__global__ __launch_bounds__(256) void combine_kernel(
    const _Float16* __restrict__ Op01, const _Float16* __restrict__ Op23,
    const float* __restrict__ ml, float* __restrict__ out)
{
    const int idx = blockIdx.x * 256 + threadIdx.x;
    const int row = idx >> 2, dq = (idx & 3) * 64;
    float m_s[NS], l_s[NS], w[NS];
    float M = -1e30f;
#pragma unroll
    for (int s = 0; s < NS; ++s) {
        m_s[s] = ml[((size_t)s * 16384 + row) * 2];
        l_s[s] = ml[((size_t)s * 16384 + row) * 2 + 1];
        M = fmaxf(M, m_s[s]);
    }
    float Wsum = 0.f;
#pragma unroll
    for (int s = 0; s < NS; ++s) { w[s] = l_s[s] * exp2f(m_s[s] - M); Wsum += w[s]; }
    const float inv = 1.0f / Wsum;
#pragma unroll
    for (int s = 0; s < NS; ++s) w[s] *= inv;

#pragma unroll
    for (int ch = 0; ch < 8; ++ch) {
        const int d0 = dq + ch * 8;
        float acc[8] = {0.f, 0.f, 0.f, 0.f, 0.f, 0.f, 0.f, 0.f};
#pragma unroll
        for (int s = 0; s < NS; ++s) {
            const _Float16* Op = (s < 2) ? (Op01 + (size_t)s * 4194304)
                                         : (Op23 + (size_t)(s - 2) * 4194304);
            f16x8 v = *(const f16x8*)(Op + (size_t)row * 256 + d0);
#pragma unroll
            for (int j = 0; j < 8; ++j) acc[j] += w[s] * (float)v[j];
        }
        float4 o0 = {acc[0], acc[1], acc[2], acc[3]};
        float4 o1 = {acc[4], acc[5], acc[6], acc[7]};
        *(float4*)(out + (size_t)row * 256 + d0) = o0;
        *(float4*)(out + (size_t)row * 256 + d0 + 4) = o1;
    }
}

extern "C" void kernel_launch(void* const* d_in, const int* in_sizes, int n_in,
                              void* d_out, int out_size, void* d_ws, size_t ws_size,
                              hipStream_t stream) {
    const float* x  = (const float*)d_in[0];
    const float* Wq = (const float*)d_in[1];
    const float* bq = (const float*)d_in[2];
    const float* Wk = (const float*)d_in[3];
    const float* bk = (const float*)d_in[4];
    const float* Wv = (const float*)d_in[5];
    const float* bv = (const float*)d_in[6];
    float* out = (float*)d_out;

    _Float16* xh  = (_Float16*)d_ws;
    _Float16* xl  = xh  + 4194304;
    _Float16* Qf  = xl  + 4194304;
    _Float16* Kf  = Qf  + 4194304;
    _Float16* Vt  = Kf  + 4194304;
    _Float16* Wth = Vt  + 4194304;
    _Float16* Wtl = Wth + 196608;
    float*    ml  = (float*)(Wtl + 196608);
    _Float16* Op23 = (_Float16*)((char*)ml + 524288);
    const size_t need4 = (size_t)((char*)(Op23 + 2 * 4194304) - (char*)d_ws);
    const int ns = (ws_size >= need4) ? 4 : 2;

    convert_x_kernel<<<4096, 256, 0, stream>>>(x, xh, xl);
    convert_w_kernel<<<768, 256, 0, stream>>>(Wq, Wk, Wv, Wth, Wtl);
    proj_kernel<<<dim3(256, 3), 256, 0, stream>>>(xh, xl, Wth, Wtl, bq, bk, bv, Qf, Kf, Vt);
    if (ns == 4) {
        attn2_kernel<4><<<512, 256, 0, stream>>>(Qf, Kf, Vt, xh, Op23, ml);
        combine_kernel<4><<<256, 256, 0, stream>>>(xh, Op23, ml, out);
    } else {
        attn2_kernel<2><<<256, 256, 0, stream>>>(Qf, Kf, Vt, xh, xh, ml);
        combine_kernel<2><<<256, 256, 0, stream>>>(xh, xh, ml, out);
    }
}

// Round 5
// 329.546 us; speedup vs baseline: 1.5497x; 1.5497x over previous
//
#include <hip/hip_runtime.h>
#include <hip/hip_fp16.h>

// Softmax attention (mask is a no-op). B=4, S=4096, D=256, fp32 in/out.
// Round 5: r4's split-K=4 @ 2 blocks/CU broke cross-block L2 reuse
// (FETCH 663MB vs 50MB ideal -> 366us). Revert to the r1-VALIDATED dispatch
// regime (grid 256, 1 block/CU, group = blockIdx&7 -> one KV stream per XCD,
// 20.6MB fetch measured) and apply the q=32/wave efficiency win inside it:
//  - block = 4 waves x 32q = 128 q-rows, KV tile = 64 keys, split-K=2
//  - LDS 144KB: K dbuf 64K (swizzled) + V dbuf 64K ([d][64key] 128B rows,
//    8-slot XOR swizzle) + P 16K (per-wave, (q&7)<<4 XOR)
//  - tile-wide defer-max rescale (r4-validated), fp16 partials + combine

typedef _Float16 f16x8 __attribute__((ext_vector_type(8)));
typedef _Float16 f16x4 __attribute__((ext_vector_type(4)));
typedef float    f32x4 __attribute__((ext_vector_type(4)));

#define MFMA16(A, B, C) __builtin_amdgcn_mfma_f32_16x16x32_f16((A), (B), (C), 0, 0, 0)

static __device__ __forceinline__ void gload16(const _Float16* g, _Float16* l) {
    __builtin_amdgcn_global_load_lds(
        (unsigned int __attribute__((address_space(1)))*)g,
        (unsigned int __attribute__((address_space(3)))*)l, 16, 0, 0);
}

// ---------------- kernel 0: convert x to fp16 hi/lo ----------------
__global__ __launch_bounds__(256) void convert_x_kernel(
    const float* __restrict__ x, _Float16* __restrict__ xh, _Float16* __restrict__ xl)
{
    int i = blockIdx.x * 256 + threadIdx.x;
    float4 v = ((const float4*)x)[i];
    float vv0 = v.x, vv1 = v.y, vv2 = v.z, vv3 = v.w;
    f16x4 h, l;
    _Float16 h0 = (_Float16)vv0; h[0] = h0; l[0] = (_Float16)(vv0 - (float)h0);
    _Float16 h1 = (_Float16)vv1; h[1] = h1; l[1] = (_Float16)(vv1 - (float)h1);
    _Float16 h2 = (_Float16)vv2; h[2] = h2; l[2] = (_Float16)(vv2 - (float)h2);
    _Float16 h3 = (_Float16)vv3; h[3] = h3; l[3] = (_Float16)(vv3 - (float)h3);
    ((f16x4*)xh)[i] = h;
    ((f16x4*)xl)[i] = l;
}

// ---------------- kernel 1: W -> W^T hi/lo fp16 ----------------
__global__ __launch_bounds__(256) void convert_w_kernel(
    const float* __restrict__ Wq, const float* __restrict__ Wk, const float* __restrict__ Wv,
    _Float16* __restrict__ Wth, _Float16* __restrict__ Wtl)
{
    int idx = blockIdx.x * 256 + threadIdx.x;
    int mat = idx >> 16, e = idx & 65535;
    int k = e >> 8, n = e & 255;
    const float* W = (mat == 0) ? Wq : (mat == 1) ? Wk : Wv;
    float v = W[e];
    _Float16 h = (_Float16)v;
    _Float16 lo = (_Float16)(v - (float)h);
    Wth[mat * 65536 + n * 256 + k] = h;
    Wtl[mat * 65536 + n * 256 + k] = lo;
}

// ---------------- kernel 2: projections (validated round 1/4) ----------------
__global__ __launch_bounds__(256) void proj_kernel(
    const _Float16* __restrict__ xh, const _Float16* __restrict__ xl,
    const _Float16* __restrict__ Wth, const _Float16* __restrict__ Wtl,
    const float* __restrict__ bq, const float* __restrict__ bk, const float* __restrict__ bv,
    _Float16* __restrict__ Qf, _Float16* __restrict__ Kf, _Float16* __restrict__ Vt)
{
    const int mat = blockIdx.y;
    const int tid = threadIdx.x, wid = tid >> 6, lane = tid & 63;
    const int lrow = lane & 15, lgrp = lane >> 4;
    const int row0 = blockIdx.x * 64 + wid * 16;
    const _Float16* Wh = Wth + mat * 65536;
    const _Float16* Wl = Wtl + mat * 65536;
    const float* bias = (mat == 0) ? bq : (mat == 1) ? bk : bv;

    f32x4 acc[16];
#pragma unroll
    for (int i = 0; i < 16; ++i) acc[i] = f32x4{0.f, 0.f, 0.f, 0.f};

#pragma unroll
    for (int ks = 0; ks < 8; ++ks) {
        const int k0 = ks * 32 + lgrp * 8;
        f16x8 Ah = *(const f16x8*)(xh + (size_t)(row0 + lrow) * 256 + k0);
        f16x8 Al = *(const f16x8*)(xl + (size_t)(row0 + lrow) * 256 + k0);
#pragma unroll
        for (int nt = 0; nt < 16; ++nt) {
            const int n = nt * 16 + lrow;
            f16x8 Bh = *(const f16x8*)(Wh + n * 256 + k0);
            f16x8 Bl = *(const f16x8*)(Wl + n * 256 + k0);
            acc[nt] = MFMA16(Ah, Bh, acc[nt]);
            acc[nt] = MFMA16(Al, Bh, acc[nt]);
            acc[nt] = MFMA16(Ah, Bl, acc[nt]);
        }
    }

    const float LOG2E = 1.4426950408889634f;
#pragma unroll
    for (int nt = 0; nt < 16; ++nt) {
        const int n = nt * 16 + lrow;
        const float bb = bias[n];
        if (mat == 2) {
            const int m0 = row0 + lgrp * 4;
            f16x4 vv;
#pragma unroll
            for (int r = 0; r < 4; ++r) vv[r] = (_Float16)(acc[nt][r] + bb);
            *(f16x4*)(Vt + (size_t)n * 16384 + m0) = vv;
        } else {
            _Float16* dst = (mat == 0) ? Qf : Kf;
            const float s = (mat == 0) ? LOG2E : 1.0f;
#pragma unroll
            for (int r = 0; r < 4; ++r) {
                const int grow = row0 + lgrp * 4 + r;
                dst[(size_t)grow * 256 + n] = (_Float16)((acc[nt][r] + bb) * s);
            }
        }
    }
}

// ---------------- kernel 3: flash attention, q=32/wave, tile=64, split-K=2 ----
// grid 256, 1 block/CU. group = hw&7 -> (b, split); 32 q-blocks per group
// share one 2MB KV stream per XCD (r1-validated flocking).
__global__ __launch_bounds__(256) void attn3_kernel(
    const _Float16* __restrict__ Qf, const _Float16* __restrict__ Kf,
    const _Float16* __restrict__ Vt, _Float16* __restrict__ Op,
    float* __restrict__ ml)
{
    __shared__ _Float16 Kb[2][64 * 256];   // [key][d], 512B rows, 32-slot swz
    __shared__ _Float16 Vb[2][256 * 64];   // [d][key], 128B rows, 8-slot swz
    __shared__ _Float16 Pb[4][32 * 64];    // per-wave P [q][key], 128B rows

    const int tid = threadIdx.x, wid = tid >> 6, lane = tid & 63;
    const int lrow = lane & 15, lgrp = lane >> 4;

    const int hw = blockIdx.x;
    const int group = hw & 7;              // -> XCD under 1-block/CU round-robin
    const int qi = hw >> 3;                // [0,32) q-block within group
    const int b = group >> 1, split = group & 1;
    const size_t bS = (size_t)b * 4096;
    const size_t qrow = bS + qi * 128 + wid * 32;        // wave's first q row
    const size_t k0g = bS + (size_t)split * 2048;        // split's key base
    const int NT = 32;                                   // 2048 keys / 64

    // Q resident: 32 q x 256 d per wave
    f16x8 Aq[2][8];
#pragma unroll
    for (int m = 0; m < 2; ++m)
#pragma unroll
        for (int ks = 0; ks < 8; ++ks)
            Aq[m][ks] = *(const f16x8*)(Qf + (qrow + m * 16 + lrow) * 256 + ks * 32 + lgrp * 8);

    f32x4 Oacc[2][16];
#pragma unroll
    for (int m = 0; m < 2; ++m)
#pragma unroll
        for (int i = 0; i < 16; ++i) Oacc[m][i] = f32x4{0.f, 0.f, 0.f, 0.f};
    float m_r[2][4], l_r[2][4];
#pragma unroll
    for (int m = 0; m < 2; ++m)
#pragma unroll
        for (int r = 0; r < 4; ++r) { m_r[m][r] = -1e30f; l_r[m][r] = 0.f; }

    _Float16* Pw = Pb[wid];

    auto stage = [&](int buf, int t) {
        const size_t krow = k0g + (size_t)t * 64;
#pragma unroll
        for (int it = 0; it < 8; ++it) {   // K: 2048 x 16B slots, swizzled src
            const int s = it * 256 + tid;
            const int row = s >> 5, c16 = s & 31;
            gload16(Kf + (krow + row) * 256 + ((c16 ^ (row & 7)) * 8), &Kb[buf][s * 8]);
        }
#pragma unroll
        for (int it = 0; it < 8; ++it) {   // V^T: 2048 x 16B slots, 8-slot swz
            const int s = it * 256 + tid;
            const int d = s >> 3, c8 = s & 7;
            gload16(Vt + (size_t)d * 16384 + krow + ((c8 ^ (d & 7)) * 8), &Vb[buf][s * 8]);
        }
    };

    stage(0, 0);
    asm volatile("s_waitcnt vmcnt(0)" ::: "memory");
    __builtin_amdgcn_s_barrier();

    const float THR = 10.0f;   // defer-max threshold (log2 domain)
    for (int t = 0; t < NT; ++t) {
        const int cur = t & 1;
        if (t + 1 < NT) stage(cur ^ 1, t + 1);
        const _Float16* K_ = Kb[cur];
        const _Float16* V_ = Vb[cur];

        // ---- QK: 32q x 64k, fp32 accum (log2 domain via Q scale) ----
        f32x4 sc[4][2];  // [key chunk][m]
#pragma unroll
        for (int nt = 0; nt < 4; ++nt) {
            sc[nt][0] = f32x4{0.f, 0.f, 0.f, 0.f};
            sc[nt][1] = f32x4{0.f, 0.f, 0.f, 0.f};
            const int key = nt * 16 + lrow;
#pragma unroll
            for (int ks = 0; ks < 8; ++ks) {
                f16x8 Bk = *(const f16x8*)(K_ + key * 256 + (((ks * 4 + lgrp) ^ (key & 7)) * 8));
                sc[nt][0] = MFMA16(Aq[0][ks], Bk, sc[nt][0]);
                sc[nt][1] = MFMA16(Aq[1][ks], Bk, sc[nt][1]);
            }
        }

        // ---- ONE tile-wide rescale decision (r4-validated) ----
        bool ok = true;
        float mxt[2][4];
#pragma unroll
        for (int m = 0; m < 2; ++m)
#pragma unroll
            for (int r = 0; r < 4; ++r) {
                float v = fmaxf(fmaxf(sc[0][m][r], sc[1][m][r]),
                                fmaxf(sc[2][m][r], sc[3][m][r]));
#pragma unroll
                for (int off = 8; off > 0; off >>= 1) v = fmaxf(v, __shfl_xor(v, off));
                mxt[m][r] = v;
                ok = ok && (v <= m_r[m][r] + THR);
            }
        if (!__all(ok)) {
#pragma unroll
            for (int m = 0; m < 2; ++m)
#pragma unroll
                for (int r = 0; r < 4; ++r) {
                    const float mn = fmaxf(m_r[m][r], mxt[m][r]);
                    const float scl = exp2f(m_r[m][r] - mn);
                    m_r[m][r] = mn;
                    l_r[m][r] *= scl;
#pragma unroll
                    for (int nt2 = 0; nt2 < 16; ++nt2) Oacc[m][nt2][r] *= scl;
                }
        }

        // ---- P = exp2(sc - m_r); row q (local, 128B), slot XOR (q&7)<<4 ----
#pragma unroll
        for (int m = 0; m < 2; ++m)
#pragma unroll
            for (int r = 0; r < 4; ++r) {
                const int q = m * 16 + lgrp * 4 + r;        // local q row
                const int qx = (q & 7) << 4;
                float rs = 0.f;
#pragma unroll
                for (int nt = 0; nt < 4; ++nt) {
                    const float p = exp2f(sc[nt][m][r] - m_r[m][r]);
                    rs += p;
                    *(_Float16*)((char*)Pw + q * 128 + ((nt * 32 + lrow * 2) ^ qx)) = (_Float16)p;
                }
#pragma unroll
                for (int off = 8; off > 0; off >>= 1) rs += __shfl_xor(rs, off);
                l_r[m][r] += rs;
            }

        // ---- PV: O[32q x 256d] += P * V ----
        asm volatile("s_waitcnt lgkmcnt(0)" ::: "memory");
        __builtin_amdgcn_sched_barrier(0);
        f16x8 Ap[2][2];   // [m][kstep]
#pragma unroll
        for (int m = 0; m < 2; ++m)
#pragma unroll
            for (int kstep = 0; kstep < 2; ++kstep) {
                const int q2 = m * 16 + lrow;
                Ap[m][kstep] = *(const f16x8*)((const char*)Pw + q2 * 128 +
                               ((kstep * 64 + lgrp * 16) ^ ((q2 & 7) << 4)));
            }
#pragma unroll
        for (int nt = 0; nt < 16; ++nt) {
            const int d = nt * 16 + lrow;
#pragma unroll
            for (int kstep = 0; kstep < 2; ++kstep) {
                f16x8 Bv = *(const f16x8*)(V_ + d * 64 + (((kstep * 4 + lgrp) ^ (d & 7)) * 8));
                Oacc[0][nt] = MFMA16(Ap[0][kstep], Bv, Oacc[0][nt]);
                Oacc[1][nt] = MFMA16(Ap[1][kstep], Bv, Oacc[1][nt]);
            }
        }

        asm volatile("s_waitcnt vmcnt(0)" ::: "memory");
        __builtin_amdgcn_s_barrier();
    }

    // ---- epilogue: normalized fp16 partial + (m, l) ----
    _Float16* Ops = Op + (size_t)split * 4194304;
#pragma unroll
    for (int m = 0; m < 2; ++m)
#pragma unroll
        for (int r = 0; r < 4; ++r) {
            const float inv = 1.0f / l_r[m][r];
            const size_t grow = qrow + m * 16 + lgrp * 4 + r;
#pragma unroll
            for (int nt = 0; nt < 16; ++nt) {
                const int d = nt * 16 + lrow;
                Ops[grow * 256 + d] = (_Float16)(Oacc[m][nt][r] * inv);
            }
            if (lrow == 0) {
                ml[((size_t)split * 16384 + grow) * 2]     = m_r[m][r];
                ml[((size_t)split * 16384 + grow) * 2 + 1] = l_r[m][r];
            }
        }
}

// ---------------- kernel 4: combine split-K partials (NS=2) ----------------
__global__ __launch_bounds__(256) void combine_kernel(
    const _Float16* __restrict__ Op, const float* __restrict__ ml,
    float* __restrict__ out)
{
    const int idx = blockIdx.x * 256 + threadIdx.x;
    const int row = idx >> 2, dq = (idx & 3) * 64;
    float m_s[2], l_s[2], w[2];
    float M = -1e30f;
#pragma unroll
    for (int s = 0; s < 2; ++s) {
        m_s[s] = ml[((size_t)s * 16384 + row) * 2];
        l_s[s] = ml[((size_t)s * 16384 + row) * 2 + 1];
        M = fmaxf(M, m_s[s]);
    }
    float Wsum = 0.f;
#pragma unroll
    for (int s = 0; s < 2; ++s) { w[s] = l_s[s] * exp2f(m_s[s] - M); Wsum += w[s]; }
    const float inv = 1.0f / Wsum;
#pragma unroll
    for (int s = 0; s < 2; ++s) w[s] *= inv;

#pragma unroll
    for (int ch = 0; ch < 8; ++ch) {
        const int d0 = dq + ch * 8;
        float acc[8] = {0.f, 0.f, 0.f, 0.f, 0.f, 0.f, 0.f, 0.f};
#pragma unroll
        for (int s = 0; s < 2; ++s) {
            f16x8 v = *(const f16x8*)(Op + (size_t)s * 4194304 + (size_t)row * 256 + d0);
#pragma unroll
            for (int j = 0; j < 8; ++j) acc[j] += w[s] * (float)v[j];
        }
        float4 o0 = {acc[0], acc[1], acc[2], acc[3]};
        float4 o1 = {acc[4], acc[5], acc[6], acc[7]};
        *(float4*)(out + (size_t)row * 256 + d0) = o0;
        *(float4*)(out + (size_t)row * 256 + d0 + 4) = o1;
    }
}

extern "C" void kernel_launch(void* const* d_in, const int* in_sizes, int n_in,
                              void* d_out, int out_size, void* d_ws, size_t ws_size,
                              hipStream_t stream) {
    const float* x  = (const float*)d_in[0];
    const float* Wq = (const float*)d_in[1];
    const float* bq = (const float*)d_in[2];
    const float* Wk = (const float*)d_in[3];
    const float* bk = (const float*)d_in[4];
    const float* Wv = (const float*)d_in[5];
    const float* bv = (const float*)d_in[6];
    float* out = (float*)d_out;

    // ws: xh/xl (reused as Op splits 0/1 after proj) | Qf | Kf | Vt | W | ml
    _Float16* xh  = (_Float16*)d_ws;
    _Float16* xl  = xh  + 4194304;
    _Float16* Qf  = xl  + 4194304;
    _Float16* Kf  = Qf  + 4194304;
    _Float16* Vt  = Kf  + 4194304;
    _Float16* Wth = Vt  + 4194304;
    _Float16* Wtl = Wth + 196608;
    float*    ml  = (float*)(Wtl + 196608);   // 2*16384*2 f32 = 256KB

    convert_x_kernel<<<4096, 256, 0, stream>>>(x, xh, xl);
    convert_w_kernel<<<768, 256, 0, stream>>>(Wq, Wk, Wv, Wth, Wtl);
    proj_kernel<<<dim3(256, 3), 256, 0, stream>>>(xh, xl, Wth, Wtl, bq, bk, bv, Qf, Kf, Vt);
    attn3_kernel<<<256, 256, 0, stream>>>(Qf, Kf, Vt, xh, ml);   // Op = xh/xl
    combine_kernel<<<256, 256, 0, stream>>>(xh, ml, out);
}